// Round 1
// baseline (84.835 us; speedup 1.0000x reference)
//
#include <hip/hip_runtime.h>
#include <hip/hip_bf16.h>
#include <stdint.h>

#define BATCH 8192
#define NSAMP 10
#define FDIM 128
#define K2 256
#define EDIM 128
#define NLAB 16384
#define EPSF 1e-6f

typedef __bf16 bf16x8 __attribute__((ext_vector_type(8)));
typedef float f32x4 __attribute__((ext_vector_type(4)));

// ---------------- W fp32 -> bf16 ----------------
__global__ void convert_w(const float* __restrict__ W, __hip_bfloat16* __restrict__ Wb) {
    int i = blockIdx.x * 256 + threadIdx.x;
    if (i < EDIM * K2) Wb[i] = __float2bfloat16(W[i]);
}

// ---------------- gather self + neighbor-mean -> combined bf16 [BATCH][256] ----------------
__global__ __launch_bounds__(256) void gather_combined(
    const int* __restrict__ nodes, const int* __restrict__ neigh,
    const float* __restrict__ feats, __hip_bfloat16* __restrict__ C)
{
    int wid  = (blockIdx.x * 256 + threadIdx.x) >> 6;   // one wave per batch row
    int lane = threadIdx.x & 63;
    if (wid >= BATCH) return;

    int n = nodes[wid];
    const float2* srow = (const float2*)(feats + (size_t)n * FDIM);
    float2 s = srow[lane];                               // 64 lanes x 8B = full row

    float ax = 0.f, ay = 0.f;
    #pragma unroll
    for (int j = 0; j < NSAMP; ++j) {
        int id = neigh[wid * NSAMP + j];
        const float2* r = (const float2*)(feats + (size_t)id * FDIM);
        float2 v = r[lane];
        ax += v.x; ay += v.y;
    }
    ax *= 0.1f; ay *= 0.1f;

    __hip_bfloat162* Crow = (__hip_bfloat162*)(C + (size_t)wid * K2);
    __hip_bfloat162 h;
    h.x = __float2bfloat16(s.x); h.y = __float2bfloat16(s.y);
    Crow[lane] = h;                                      // k = 2*lane (self half)
    h.x = __float2bfloat16(ax); h.y = __float2bfloat16(ay);
    Crow[64 + lane] = h;                                 // k = 128 + 2*lane (neigh half)
}

// ---------------- out[128][8192] = relu(W @ C^T), bf16 MFMA ----------------
__global__ __launch_bounds__(256) void gemm_relu(
    const __hip_bfloat16* __restrict__ Wb,   // [128][256] row-major
    const __hip_bfloat16* __restrict__ C,    // [8192][256] row-major
    float* __restrict__ out)                 // [128][8192]
{
    int lane = threadIdx.x & 63;
    int wave = threadIdx.x >> 6;
    int wm = wave >> 1;                       // 2 waves along M
    int wn = wave & 1;                        // 2 waves along N
    int m0 = wm * 64;
    int n0 = blockIdx.x * 64 + wn * 32;
    int llo = lane & 15, lhi = lane >> 4;

    f32x4 acc[4][2];
    #pragma unroll
    for (int i = 0; i < 4; ++i)
        #pragma unroll
        for (int j = 0; j < 2; ++j) { f32x4 z = {0.f,0.f,0.f,0.f}; acc[i][j] = z; }

    #pragma unroll
    for (int k0 = 0; k0 < K2; k0 += 32) {
        bf16x8 a[4], b[2];
        #pragma unroll
        for (int mi = 0; mi < 4; ++mi) {
            const uint4* p = (const uint4*)(Wb + (size_t)(m0 + 16*mi + llo) * K2 + k0 + lhi*8);
            a[mi] = __builtin_bit_cast(bf16x8, *p);
        }
        #pragma unroll
        for (int ni = 0; ni < 2; ++ni) {
            const uint4* p = (const uint4*)(C + (size_t)(n0 + 16*ni + llo) * K2 + k0 + lhi*8);
            b[ni] = __builtin_bit_cast(bf16x8, *p);
        }
        #pragma unroll
        for (int mi = 0; mi < 4; ++mi)
            #pragma unroll
            for (int ni = 0; ni < 2; ++ni)
                acc[mi][ni] = __builtin_amdgcn_mfma_f32_16x16x32_bf16(a[mi], b[ni], acc[mi][ni], 0, 0, 0);
    }

    #pragma unroll
    for (int mi = 0; mi < 4; ++mi)
        #pragma unroll
        for (int ni = 0; ni < 2; ++ni)
            #pragma unroll
            for (int j = 0; j < 4; ++j) {
                int row = m0 + 16*mi + lhi*4 + j;   // C/D: col=lane&15, row=(lane>>4)*4+reg
                int col = n0 + 16*ni + llo;
                out[(size_t)row * BATCH + col] = fmaxf(acc[mi][ni][j], 0.f);
            }
}

// ---------------- update_vector stage 1: per-wave partials ----------------
// partial layout: [2][256 waves][132]  (128 accs + esum at [128])
__global__ __launch_bounds__(256) void update_stage1(
    const int* __restrict__ pos_idx, const int* __restrict__ neg_idx,
    const float* __restrict__ feats,
    const float* __restrict__ pos_vec, const float* __restrict__ neg_vec,
    float* __restrict__ partial)
{
    int sel = blockIdx.y;
    const int*   idx = sel ? neg_idx : pos_idx;
    const float* vec = sel ? neg_vec : pos_vec;
    int lane = threadIdx.x & 63;
    int wid  = blockIdx.x * 4 + (threadIdx.x >> 6);     // 0..255

    float2 v = ((const float2*)vec)[lane];
    float pv = v.x*v.x + v.y*v.y;
    #pragma unroll
    for (int off = 32; off; off >>= 1) pv += __shfl_xor(pv, off);
    float nv = fmaxf(sqrtf(pv), EPSF);
    float inv5nv = 1.f / (5.f * nv);

    float a0 = 0.f, a1 = 0.f, es = 0.f;
    int base = wid * 64;
    for (int r = 0; r < 64; ++r) {
        int id = idx[base + r];
        float2 x = ((const float2*)(feats + (size_t)id * FDIM))[lane];
        float d  = x.x*v.x + x.y*v.y;
        float nx = x.x*x.x + x.y*x.y;
        #pragma unroll
        for (int off = 32; off; off >>= 1) {
            d  += __shfl_xor(d, off);
            nx += __shfl_xor(nx, off);
        }
        nx = fmaxf(sqrtf(nx), EPSF);
        float e = __expf(d * inv5nv / nx);   // cos/5 in [-0.2,0.2]: no max-sub needed
        es += e;
        a0 += e * x.x; a1 += e * x.y;
    }
    float* pw = partial + ((size_t)sel * 256 + wid) * 132;
    float2 w2; w2.x = a0; w2.y = a1;
    ((float2*)pw)[lane] = w2;
    if (lane == 0) pw[128] = es;
}

// ---------------- update_vector stage 2: reduce partials ----------------
__global__ void update_stage2(const float* __restrict__ partial, float* __restrict__ outv) {
    int sel = blockIdx.x;           // 0 pos, 1 neg
    int d   = threadIdx.x;          // 0..127
    const float* p = partial + (size_t)sel * 256 * 132;
    float s = 0.f, es = 0.f;
    for (int w = 0; w < 256; ++w) {
        s  += p[w * 132 + d];
        es += p[w * 132 + 128];
    }
    outv[sel * 128 + d] = s / es;
}

extern "C" void kernel_launch(void* const* d_in, const int* in_sizes, int n_in,
                              void* d_out, int out_size, void* d_ws, size_t ws_size,
                              hipStream_t stream) {
    const int*   nodes = (const int*)d_in[0];
    const int*   neigh = (const int*)d_in[1];
    const int*   pos_i = (const int*)d_in[2];
    const int*   neg_i = (const int*)d_in[3];
    const float* feats = (const float*)d_in[4];
    const float* W     = (const float*)d_in[5];
    const float* pvec  = (const float*)d_in[6];
    const float* nvec  = (const float*)d_in[7];
    float* out = (float*)d_out;

    char* ws = (char*)d_ws;
    __hip_bfloat16* C  = (__hip_bfloat16*)ws;               // 8192*256*2 = 4,194,304 B
    __hip_bfloat16* Wb = (__hip_bfloat16*)(ws + 4194304);   // 65,536 B
    float* partial     = (float*)(ws + 4259840);            // 2*256*132*4 = 270,336 B

    hipLaunchKernelGGL(convert_w,       dim3(128),    dim3(256), 0, stream, W, Wb);
    hipLaunchKernelGGL(gather_combined, dim3(2048),   dim3(256), 0, stream, nodes, neigh, feats, C);
    hipLaunchKernelGGL(gemm_relu,       dim3(128),    dim3(256), 0, stream, Wb, C, out);
    hipLaunchKernelGGL(update_stage1,   dim3(64, 2),  dim3(256), 0, stream, pos_i, neg_i, feats, pvec, nvec, partial);
    hipLaunchKernelGGL(update_stage2,   dim3(2),      dim3(128), 0, stream, partial, out + 1048576);
}

// Round 2
// 46.374 us; speedup vs baseline: 1.8293x; 1.8293x over previous
//
#include <hip/hip_runtime.h>
#include <hip/hip_bf16.h>
#include <stdint.h>

#define BATCH 8192
#define NSAMP 10
#define FDIM 128
#define K2 256
#define EDIM 128
#define NLAB 16384
#define EPSF 1e-6f

typedef __bf16 bf16x8 __attribute__((ext_vector_type(8)));
typedef float f32x4 __attribute__((ext_vector_type(4)));

struct alignas(8) bfx4 { __hip_bfloat16 a, b, c, d; };

// partial layout: [2][2048][132] (128 accs + esum at [128])
#define NPART 2048

// ================= Kernel A: gather+mean (blocks 0..1023), update stage1
// (blocks 1024..2047), W convert (block 2048) =================
__global__ __launch_bounds__(256) void fusedA(
    const int* __restrict__ nodes, const int* __restrict__ neigh,
    const int* __restrict__ pos_idx, const int* __restrict__ neg_idx,
    const float* __restrict__ feats,
    const float* __restrict__ pos_vec, const float* __restrict__ neg_vec,
    const float* __restrict__ W,
    __hip_bfloat16* __restrict__ C, __hip_bfloat16* __restrict__ Wb,
    float* __restrict__ partial)
{
    int blk  = blockIdx.x;
    int tid  = threadIdx.x;
    int lane = tid & 63;
    int wv   = tid >> 6;
    int hl   = lane & 31;        // lane within half-wave
    int half = lane >> 5;        // 0 or 1

    if (blk < 1024) {
        // ---- gather self + neighbor mean: one wave = 2 batch rows ----
        int pair = blk * 4 + wv;
        int row  = 2 * pair + half;          // each half-wave owns one row
        // self features: 32 lanes x float4 = full 128-f row
        int n = nodes[row];
        f32x4 s = ((const f32x4*)(feats + (size_t)n * FDIM))[hl];
        // neighbor mean
        f32x4 acc = {0.f, 0.f, 0.f, 0.f};
        #pragma unroll
        for (int j = 0; j < NSAMP; ++j) {
            int id = neigh[row * NSAMP + j];
            f32x4 v = ((const f32x4*)(feats + (size_t)id * FDIM))[hl];
            acc += v;
        }
        acc *= 0.1f;
        __hip_bfloat16* Crow = C + (size_t)row * K2;
        bfx4 t;
        t.a = __float2bfloat16(s[0]); t.b = __float2bfloat16(s[1]);
        t.c = __float2bfloat16(s[2]); t.d = __float2bfloat16(s[3]);
        *(bfx4*)(Crow + 4 * hl) = t;
        t.a = __float2bfloat16(acc[0]); t.b = __float2bfloat16(acc[1]);
        t.c = __float2bfloat16(acc[2]); t.d = __float2bfloat16(acc[3]);
        *(bfx4*)(Crow + FDIM + 4 * hl) = t;
    } else if (blk < 2048) {
        // ---- update_vector stage 1: one wave = 8 rows (2 at a time in halves) ----
        int b     = blk - 1024;
        int sel   = b >> 9;                  // 512 blocks pos, 512 neg
        int inner = b & 511;
        int wid   = inner * 4 + wv;          // 0..2047
        const int*   idx = sel ? neg_idx : pos_idx;
        const float* vec = sel ? neg_vec : pos_vec;

        f32x4 v4 = ((const f32x4*)vec)[hl];  // full vec per half-wave
        float pv = v4[0]*v4[0] + v4[1]*v4[1] + v4[2]*v4[2] + v4[3]*v4[3];
        #pragma unroll
        for (int off = 16; off; off >>= 1) pv += __shfl_xor(pv, off);
        float inv5nv = 1.f / (5.f * fmaxf(sqrtf(pv), EPSF));

        f32x4 a4 = {0.f, 0.f, 0.f, 0.f};
        float es = 0.f;
        int base = wid * 8;
        #pragma unroll
        for (int it = 0; it < 4; ++it) {
            int id = idx[base + 2 * it + half];
            f32x4 x = ((const f32x4*)(feats + (size_t)id * FDIM))[hl];
            float d  = x[0]*v4[0] + x[1]*v4[1] + x[2]*v4[2] + x[3]*v4[3];
            float nx = x[0]*x[0] + x[1]*x[1] + x[2]*x[2] + x[3]*x[3];
            #pragma unroll
            for (int off = 16; off; off >>= 1) {
                d  += __shfl_xor(d, off);
                nx += __shfl_xor(nx, off);
            }
            nx = fmaxf(sqrtf(nx), EPSF);
            float e = __expf(d * inv5nv / nx);   // cos/5 in [-0.2,0.2]: no max-sub
            es += e;
            a4 += e * x;
        }
        // combine halves (different rows, same feature cols)
        #pragma unroll
        for (int c = 0; c < 4; ++c) a4[c] += __shfl_xor(a4[c], 32);
        es += __shfl_xor(es, 32);
        float* pw = partial + ((size_t)sel * NPART + wid) * 132;
        if (lane < 32) ((f32x4*)pw)[lane] = a4;
        if (lane == 0) pw[128] = es;
    } else {
        // ---- W fp32 -> bf16 ----
        for (int i = tid; i < EDIM * K2; i += 256)
            Wb[i] = __float2bfloat16(W[i]);
    }
}

// ================= Kernel B: gemm+relu (blocks 0..255), stage2 (blocks 256..319)
__global__ __launch_bounds__(256) void fusedB(
    const __hip_bfloat16* __restrict__ Wb,   // [128][256] row-major
    const __hip_bfloat16* __restrict__ C,    // [8192][256] row-major
    const float* __restrict__ partial,
    float* __restrict__ out)                 // [128][8192] then pos[128], neg[128]
{
    int tid  = threadIdx.x;
    int lane = tid & 63;
    int wv   = tid >> 6;

    if (blockIdx.x < 256) {
        int llo = lane & 15, lhi = lane >> 4;
        int m0 = wv * 32;
        int n0 = blockIdx.x * 32;

        f32x4 acc[2][2];
        #pragma unroll
        for (int i = 0; i < 2; ++i)
            #pragma unroll
            for (int j = 0; j < 2; ++j) { f32x4 z = {0.f,0.f,0.f,0.f}; acc[i][j] = z; }

        #pragma unroll
        for (int k0 = 0; k0 < K2; k0 += 32) {
            bf16x8 a[2], b[2];
            #pragma unroll
            for (int mi = 0; mi < 2; ++mi) {
                const uint4* p = (const uint4*)(Wb + (size_t)(m0 + 16*mi + llo) * K2 + k0 + lhi*8);
                a[mi] = __builtin_bit_cast(bf16x8, *p);
            }
            #pragma unroll
            for (int ni = 0; ni < 2; ++ni) {
                const uint4* p = (const uint4*)(C + (size_t)(n0 + 16*ni + llo) * K2 + k0 + lhi*8);
                b[ni] = __builtin_bit_cast(bf16x8, *p);
            }
            #pragma unroll
            for (int mi = 0; mi < 2; ++mi)
                #pragma unroll
                for (int ni = 0; ni < 2; ++ni)
                    acc[mi][ni] = __builtin_amdgcn_mfma_f32_16x16x32_bf16(a[mi], b[ni], acc[mi][ni], 0, 0, 0);
        }

        #pragma unroll
        for (int mi = 0; mi < 2; ++mi)
            #pragma unroll
            for (int ni = 0; ni < 2; ++ni)
                #pragma unroll
                for (int j = 0; j < 4; ++j) {
                    int row = m0 + 16*mi + lhi*4 + j;   // C/D: col=lane&15, row=(lane>>4)*4+reg
                    int col = n0 + 16*ni + llo;
                    out[(size_t)row * BATCH + col] = fmaxf(acc[mi][ni][j], 0.f);
                }
    } else {
        // ---- stage2: one wave per (sel, d) ----
        int widx = (blockIdx.x - 256) * 4 + wv;   // 0..255
        int sel = widx >> 7;
        int d   = widx & 127;
        const float* p = partial + (size_t)sel * NPART * 132;
        float s = 0.f, es = 0.f;
        for (int w = lane; w < NPART; w += 64) {
            s  += p[w * 132 + d];
            es += p[w * 132 + 128];
        }
        #pragma unroll
        for (int off = 32; off; off >>= 1) {
            s  += __shfl_xor(s, off);
            es += __shfl_xor(es, off);
        }
        if (lane == 0) out[1048576 + sel * 128 + d] = s / es;
    }
}

extern "C" void kernel_launch(void* const* d_in, const int* in_sizes, int n_in,
                              void* d_out, int out_size, void* d_ws, size_t ws_size,
                              hipStream_t stream) {
    const int*   nodes = (const int*)d_in[0];
    const int*   neigh = (const int*)d_in[1];
    const int*   pos_i = (const int*)d_in[2];
    const int*   neg_i = (const int*)d_in[3];
    const float* feats = (const float*)d_in[4];
    const float* W     = (const float*)d_in[5];
    const float* pvec  = (const float*)d_in[6];
    const float* nvec  = (const float*)d_in[7];
    float* out = (float*)d_out;

    char* ws = (char*)d_ws;
    __hip_bfloat16* C  = (__hip_bfloat16*)ws;               // 4,194,304 B
    __hip_bfloat16* Wb = (__hip_bfloat16*)(ws + 4194304);   // 65,536 B
    float* partial     = (float*)(ws + 4259840);            // 2*2048*132*4 = 2,162,688 B

    hipLaunchKernelGGL(fusedA, dim3(2049), dim3(256), 0, stream,
                       nodes, neigh, pos_i, neg_i, feats, pvec, nvec, W, C, Wb, partial);
    hipLaunchKernelGGL(fusedB, dim3(320), dim3(256), 0, stream,
                       Wb, C, partial, out);
}

// Round 3
// 33.219 us; speedup vs baseline: 2.5538x; 1.3960x over previous
//
#include <hip/hip_runtime.h>
#include <hip/hip_bf16.h>
#include <stdint.h>

#define BATCH 8192
#define NSAMP 10
#define FDIM 128
#define K2 256
#define EDIM 128
#define NLAB 16384
#define EPSF 1e-6f

#define CPAD 264   // 256 + 8 bf16 pad -> 528B row stride, 16B aligned, 2-way bank alias (free)

typedef __bf16 bf16x8 __attribute__((ext_vector_type(8)));
typedef float f32x4 __attribute__((ext_vector_type(4)));

struct alignas(8) bfx4 { __hip_bfloat16 a, b, c, d; };

#define NPART 2048   // stage1 waves per sel

// ================= Kernel A =================
// blocks 0..255   : gather 32 batch rows -> LDS, then 128x32 GEMM tile + relu
// blocks 256..1279: update_vector stage 1
__global__ __launch_bounds__(256) void fusedA(
    const int* __restrict__ nodes, const int* __restrict__ neigh,
    const int* __restrict__ pos_idx, const int* __restrict__ neg_idx,
    const float* __restrict__ feats,
    const float* __restrict__ pos_vec, const float* __restrict__ neg_vec,
    const float* __restrict__ W,         // [128][256] fp32 row-major
    float* __restrict__ partial,
    float* __restrict__ out)             // [128][8192]
{
    __shared__ __hip_bfloat16 comb[32][CPAD];

    int blk  = blockIdx.x;
    int tid  = threadIdx.x;
    int lane = tid & 63;
    int wv   = tid >> 6;
    int hl   = lane & 31;        // lane within half-wave
    int half = lane >> 5;        // 0 or 1
    int hw   = wv * 2 + half;    // half-wave id 0..7

    if (blk < 256) {
        int n0 = blk * 32;       // this block's batch-row base

        // ---- phase 1: gather self + neighbor mean for 4 rows per half-wave ----
        for (int rr = 0; rr < 4; ++rr) {
            int lr  = hw * 4 + rr;           // local row 0..31
            int row = n0 + lr;
            int ids[NSAMP + 1];
            ids[0] = nodes[row];
            #pragma unroll
            for (int j = 0; j < NSAMP; ++j) ids[1 + j] = neigh[row * NSAMP + j];

            f32x4 s = ((const f32x4*)(feats + (size_t)ids[0] * FDIM))[hl];
            f32x4 acc = {0.f, 0.f, 0.f, 0.f};
            #pragma unroll
            for (int j = 0; j < NSAMP; ++j) {
                f32x4 v = ((const f32x4*)(feats + (size_t)ids[1 + j] * FDIM))[hl];
                acc += v;
            }
            acc *= 0.1f;

            bfx4 t;
            t.a = __float2bfloat16(s[0]); t.b = __float2bfloat16(s[1]);
            t.c = __float2bfloat16(s[2]); t.d = __float2bfloat16(s[3]);
            *(bfx4*)(&comb[lr][4 * hl]) = t;
            t.a = __float2bfloat16(acc[0]); t.b = __float2bfloat16(acc[1]);
            t.c = __float2bfloat16(acc[2]); t.d = __float2bfloat16(acc[3]);
            *(bfx4*)(&comb[lr][FDIM + 4 * hl]) = t;
        }
        __syncthreads();

        // ---- phase 2: out[m0..m0+31][n0..n0+31] = relu(W @ comb^T) ----
        int llo = lane & 15, lhi = lane >> 4;
        int m0 = wv * 32;

        f32x4 acc[2][2];
        #pragma unroll
        for (int i = 0; i < 2; ++i)
            #pragma unroll
            for (int j = 0; j < 2; ++j) { f32x4 z = {0.f,0.f,0.f,0.f}; acc[i][j] = z; }

        #pragma unroll
        for (int k0 = 0; k0 < K2; k0 += 32) {
            bf16x8 a[2], b[2];
            #pragma unroll
            for (int mi = 0; mi < 2; ++mi) {
                const float* wp = W + (size_t)(m0 + 16*mi + llo) * K2 + k0 + lhi*8;
                f32x4 w0 = ((const f32x4*)wp)[0];
                f32x4 w1 = ((const f32x4*)wp)[1];
                bf16x8 af;
                af[0] = (__bf16)w0[0]; af[1] = (__bf16)w0[1];
                af[2] = (__bf16)w0[2]; af[3] = (__bf16)w0[3];
                af[4] = (__bf16)w1[0]; af[5] = (__bf16)w1[1];
                af[6] = (__bf16)w1[2]; af[7] = (__bf16)w1[3];
                a[mi] = af;
            }
            #pragma unroll
            for (int ni = 0; ni < 2; ++ni) {
                const uint4* p = (const uint4*)(&comb[16*ni + llo][k0 + lhi*8]);
                b[ni] = __builtin_bit_cast(bf16x8, *p);
            }
            #pragma unroll
            for (int mi = 0; mi < 2; ++mi)
                #pragma unroll
                for (int ni = 0; ni < 2; ++ni)
                    acc[mi][ni] = __builtin_amdgcn_mfma_f32_16x16x32_bf16(a[mi], b[ni], acc[mi][ni], 0, 0, 0);
        }

        #pragma unroll
        for (int mi = 0; mi < 2; ++mi)
            #pragma unroll
            for (int ni = 0; ni < 2; ++ni)
                #pragma unroll
                for (int j = 0; j < 4; ++j) {
                    int row = m0 + 16*mi + lhi*4 + j;   // C/D: col=lane&15, row=(lane>>4)*4+reg
                    int col = n0 + 16*ni + llo;
                    out[(size_t)row * BATCH + col] = fmaxf(acc[mi][ni][j], 0.f);
                }
    } else {
        // ---- update_vector stage 1: one wave = 8 rows (2 at a time in halves) ----
        int b     = blk - 256;
        int sel   = b >> 9;                  // 512 blocks pos, 512 neg
        int inner = b & 511;
        int wid   = inner * 4 + wv;          // 0..2047
        const int*   idx = sel ? neg_idx : pos_idx;
        const float* vec = sel ? neg_vec : pos_vec;

        f32x4 v4 = ((const f32x4*)vec)[hl];  // full vec per half-wave
        float pv = v4[0]*v4[0] + v4[1]*v4[1] + v4[2]*v4[2] + v4[3]*v4[3];
        #pragma unroll
        for (int off = 16; off; off >>= 1) pv += __shfl_xor(pv, off);
        float inv5nv = 1.f / (5.f * fmaxf(sqrtf(pv), EPSF));

        f32x4 a4 = {0.f, 0.f, 0.f, 0.f};
        float es = 0.f;
        int base = wid * 8;
        #pragma unroll
        for (int it = 0; it < 4; ++it) {
            int id = idx[base + 2 * it + half];
            f32x4 x = ((const f32x4*)(feats + (size_t)id * FDIM))[hl];
            float d  = x[0]*v4[0] + x[1]*v4[1] + x[2]*v4[2] + x[3]*v4[3];
            float nx = x[0]*x[0] + x[1]*x[1] + x[2]*x[2] + x[3]*x[3];
            #pragma unroll
            for (int off = 16; off; off >>= 1) {
                d  += __shfl_xor(d, off);
                nx += __shfl_xor(nx, off);
            }
            nx = fmaxf(sqrtf(nx), EPSF);
            float e = __expf(d * inv5nv / nx);   // cos/5 in [-0.2,0.2]: no max-sub
            es += e;
            a4 += e * x;
        }
        // combine halves (different rows, same feature cols)
        #pragma unroll
        for (int c = 0; c < 4; ++c) a4[c] += __shfl_xor(a4[c], 32);
        es += __shfl_xor(es, 32);
        float* pw = partial + ((size_t)sel * NPART + wid) * 132;
        if (lane < 32) ((f32x4*)pw)[lane] = a4;
        if (lane == 0) pw[128] = es;
    }
}

// ================= Kernel B: stage2 (one wave per (sel,d)) =================
__global__ __launch_bounds__(256) void stage2k(
    const float* __restrict__ partial, float* __restrict__ outv)
{
    int lane = threadIdx.x & 63;
    int wv   = threadIdx.x >> 6;
    int widx = blockIdx.x * 4 + wv;   // 0..255
    int sel = widx >> 7;
    int d   = widx & 127;
    const float* p = partial + (size_t)sel * NPART * 132;
    float s = 0.f, es = 0.f;
    for (int w = lane; w < NPART; w += 64) {
        s  += p[w * 132 + d];
        es += p[w * 132 + 128];
    }
    #pragma unroll
    for (int off = 32; off; off >>= 1) {
        s  += __shfl_xor(s, off);
        es += __shfl_xor(es, off);
    }
    if (lane == 0) outv[sel * 128 + d] = s / es;
}

extern "C" void kernel_launch(void* const* d_in, const int* in_sizes, int n_in,
                              void* d_out, int out_size, void* d_ws, size_t ws_size,
                              hipStream_t stream) {
    const int*   nodes = (const int*)d_in[0];
    const int*   neigh = (const int*)d_in[1];
    const int*   pos_i = (const int*)d_in[2];
    const int*   neg_i = (const int*)d_in[3];
    const float* feats = (const float*)d_in[4];
    const float* W     = (const float*)d_in[5];
    const float* pvec  = (const float*)d_in[6];
    const float* nvec  = (const float*)d_in[7];
    float* out = (float*)d_out;

    float* partial = (float*)d_ws;   // 2*2048*132*4 = 2,162,688 B

    hipLaunchKernelGGL(fusedA, dim3(1280), dim3(256), 0, stream,
                       nodes, neigh, pos_i, neg_i, feats, pvec, nvec, W, partial, out);
    hipLaunchKernelGGL(stage2k, dim3(64), dim3(256), 0, stream,
                       partial, out + 1048576);
}